// Round 12
// baseline (293.308 us; speedup 1.0000x reference)
//
#include <hip/hip_runtime.h>

#define EPSF 1e-9f

typedef __attribute__((ext_vector_type(8))) short short8;
typedef __attribute__((ext_vector_type(4))) float f32x4;
typedef __attribute__((ext_vector_type(4))) unsigned int u32x4;
typedef __attribute__((ext_vector_type(2))) unsigned int u32x2;

__device__ __forceinline__ unsigned pkbf(float lo, float hi) {
  unsigned r;
  asm("v_cvt_pk_bf16_f32 %0, %1, %2" : "=v"(r) : "v"(lo), "v"(hi));
  return r;
}
__device__ __forceinline__ short8 mk8(unsigned a, unsigned b, unsigned c, unsigned d) {
  u32x4 u = {a, b, c, d};
  return __builtin_bit_cast(short8, u);
}

// ---------------- k_s: s[b,n] = (si_r, si_i, sj_r, sj_i); 8 lanes per row
__global__ __launch_bounds__(256) void k_s(
    const float* __restrict__ Xr, const float* __restrict__ Xi,
    const float* __restrict__ War, const float* __restrict__ Wai,
    float4* __restrict__ s4, float2* __restrict__ sj2)
{
  int t = threadIdx.x;
  int nf = blockIdx.x * 32 + (t >> 3);   // flat b*512+n
  int c0 = (t & 7) * 8;
  const f32x4* xr = (const f32x4*)(Xr + (size_t)nf * 64 + c0);
  const f32x4* xi = (const f32x4*)(Xi + (size_t)nf * 64 + c0);
  const f32x4* w1r = (const f32x4*)(War + c0);
  const f32x4* w2r = (const f32x4*)(War + 64 + c0);
  const f32x4* w1i = (const f32x4*)(Wai + c0);
  const f32x4* w2i = (const f32x4*)(Wai + 64 + c0);
  float sir = 0.f, sii = 0.f, sjr = 0.f, sji = 0.f;
#pragma unroll
  for (int h = 0; h < 2; ++h) {
    f32x4 a = xr[h], bb = xi[h];
    f32x4 u1r = w1r[h], u1i = w1i[h], u2r = w2r[h], u2i = w2i[h];
#pragma unroll
    for (int e = 0; e < 4; ++e) {
      sir += a[e] * u1r[e] - bb[e] * u1i[e];
      sii += a[e] * u1i[e] + bb[e] * u1r[e];
      sjr += a[e] * u2r[e] - bb[e] * u2i[e];
      sji += a[e] * u2i[e] + bb[e] * u2r[e];
    }
  }
#pragma unroll
  for (int off = 1; off < 8; off <<= 1) {
    sir += __shfl_xor(sir, off);
    sii += __shfl_xor(sii, off);
    sjr += __shfl_xor(sjr, off);
    sji += __shfl_xor(sji, off);
  }
  if ((t & 7) == 0) {
    s4[nf] = make_float4(sir, sii, sjr, sji);
    sj2[nf] = make_float2(sjr, sji);
  }
}

// ---------------- k_stats: per-(b,i) (max_r, 1/sum_r, max_i, 1/sum_i)
__global__ __launch_bounds__(256) void k_stats(
    const float4* __restrict__ s4, const float2* __restrict__ sj2,
    const float* __restrict__ bar, const float* __restrict__ bai,
    const float* __restrict__ modbp, float4* __restrict__ stats)
{
  __shared__ float2 sh[512];
  int t = threadIdx.x;
  int b = blockIdx.x >> 4;
  int i0 = (blockIdx.x & 15) * 32;
  sh[t] = sj2[(size_t)b * 512 + t];
  sh[t + 256] = sj2[(size_t)b * 512 + t + 256];
  __syncthreads();
  float ba_r = bar[0], ba_i = bai[0], modb = modbp[0];
  int i = i0 + (t >> 3), jl = t & 7;
  float4 sv = s4[(size_t)b * 512 + i];
  float sirb = sv.x + ba_r, siib = sv.y + ba_i;
  float mr = -1e30f, mi = -1e30f;
  for (int jj = 0; jj < 64; ++jj) {
    float2 sj = sh[jl * 64 + jj];
    float scr = sirb + sj.x, sci = siib + sj.y;
    float mag = sqrtf(scr * scr + sci * sci);
    float sc = fmaxf(mag + modb, 0.f) * __builtin_amdgcn_rcpf(mag + EPSF);
    mr = fmaxf(mr, scr * sc);
    mi = fmaxf(mi, sci * sc);
  }
#pragma unroll
  for (int off = 1; off < 8; off <<= 1) {
    mr = fmaxf(mr, __shfl_xor(mr, off));
    mi = fmaxf(mi, __shfl_xor(mi, off));
  }
  float er = 0.f, ei = 0.f;
  for (int jj = 0; jj < 64; ++jj) {
    float2 sj = sh[jl * 64 + jj];
    float scr = sirb + sj.x, sci = siib + sj.y;
    float mag = sqrtf(scr * scr + sci * sci);
    float sc = fmaxf(mag + modb, 0.f) * __builtin_amdgcn_rcpf(mag + EPSF);
    er += __expf(scr * sc - mr);
    ei += __expf(sci * sc - mi);
  }
#pragma unroll
  for (int off = 1; off < 8; off <<= 1) {
    er += __shfl_xor(er, off);
    ei += __shfl_xor(ei, off);
  }
  if (jl == 0)
    stats[(size_t)b * 512 + i] = make_float4(mr, 1.f / er, mi, 1.f / ei);
}

// ---------------- k_y: Y[b,k] = X[b] @ W[k] (complex), B-fragment layout.
// 960 blocks (R9-verified split): blockIdx = (b*5+k)*4 + jh; q = jh*8 + w*2 + qq.
__global__ __launch_bounds__(256) void k_y(
    const float* __restrict__ Xr, const float* __restrict__ Xi,
    const float* __restrict__ Wr, const float* __restrict__ Wi,
    u32x4* __restrict__ yfrag)
{
  __shared__ __align__(16) short WtR[64 * 72];     // [o][c] pad 72
  __shared__ __align__(16) short WtI[64 * 72];
  __shared__ __align__(16) short Yt[4][2][64 * 24]; // per-wave [o][jj] pad 24
  int bk = blockIdx.x >> 2;
  int jh = blockIdx.x & 3;
  int b = bk / 5, k = bk % 5;
  int t = threadIdx.x;
  {
    int o = t & 63, cbase = (t >> 6) * 16;
    const float* wr = Wr + (size_t)k * 4096;
    const float* wi = Wi + (size_t)k * 4096;
#pragma unroll
    for (int cc = 0; cc < 16; cc += 2) {
      int c = cbase + cc;
      *(unsigned*)&WtR[o * 72 + c] = pkbf(wr[c * 64 + o], wr[(c + 1) * 64 + o]);
      *(unsigned*)&WtI[o * 72 + c] = pkbf(wi[c * 64 + o], wi[(c + 1) * 64 + o]);
    }
  }
  __syncthreads();
  int w = t >> 6, l = t & 63;
  int lane15 = l & 15, quad = l >> 4;
  short* ytR = &Yt[w][0][0];
  short* ytI = &Yt[w][1][0];
  for (int qq = 0; qq < 2; ++qq) {
    int q = jh * 8 + w * 2 + qq;
    int j = q * 16 + lane15;
    const f32x4* pxr = (const f32x4*)(Xr + ((size_t)b * 512 + j) * 64 + quad * 8);
    const f32x4* pxi = (const f32x4*)(Xi + ((size_t)b * 512 + j) * 64 + quad * 8);
    f32x4 xr0 = pxr[0], xr1 = pxr[1], xr8 = pxr[8], xr9 = pxr[9];
    f32x4 xi0 = pxi[0], xi1 = pxi[1], xi8 = pxi[8], xi9 = pxi[9];
    short8 axr[2], axi[2];
    axr[0] = mk8(pkbf(xr0[0], xr0[1]), pkbf(xr0[2], xr0[3]), pkbf(xr1[0], xr1[1]), pkbf(xr1[2], xr1[3]));
    axr[1] = mk8(pkbf(xr8[0], xr8[1]), pkbf(xr8[2], xr8[3]), pkbf(xr9[0], xr9[1]), pkbf(xr9[2], xr9[3]));
    axi[0] = mk8(pkbf(xi0[0], xi0[1]), pkbf(xi0[2], xi0[3]), pkbf(xi1[0], xi1[1]), pkbf(xi1[2], xi1[3]));
    axi[1] = mk8(pkbf(xi8[0], xi8[1]), pkbf(xi8[2], xi8[3]), pkbf(xi9[0], xi9[1]), pkbf(xi9[2], xi9[3]));
    f32x4 aR1[4], aR2[4], aI[4];
#pragma unroll
    for (int os = 0; os < 4; ++os) {
      aR1[os] = f32x4{0.f, 0.f, 0.f, 0.f};
      aR2[os] = f32x4{0.f, 0.f, 0.f, 0.f};
      aI[os] = f32x4{0.f, 0.f, 0.f, 0.f};
    }
#pragma unroll
    for (int kc = 0; kc < 2; ++kc) {
#pragma unroll
      for (int os = 0; os < 4; ++os) {
        int widx = (os * 16 + lane15) * 72 + kc * 32 + quad * 8;
        short8 wrF = *(const short8*)&WtR[widx];
        short8 wiF = *(const short8*)&WtI[widx];
        aR1[os] = __builtin_amdgcn_mfma_f32_16x16x32_bf16(axr[kc], wrF, aR1[os], 0, 0, 0);
        aR2[os] = __builtin_amdgcn_mfma_f32_16x16x32_bf16(axi[kc], wiF, aR2[os], 0, 0, 0);
        aI[os]  = __builtin_amdgcn_mfma_f32_16x16x32_bf16(axr[kc], wiF, aI[os], 0, 0, 0);
        aI[os]  = __builtin_amdgcn_mfma_f32_16x16x32_bf16(axi[kc], wrF, aI[os], 0, 0, 0);
      }
    }
#pragma unroll
    for (int os = 0; os < 4; ++os) {
      f32x4 R = aR1[os] - aR2[os];
      f32x4 I = aI[os];
      int ya = (os * 16 + lane15) * 24 + quad * 4;
      *(u32x2*)&ytR[ya] = u32x2{pkbf(R[0], R[1]), pkbf(R[2], R[3])};
      *(u32x2*)&ytI[ya] = u32x2{pkbf(I[0], I[1]), pkbf(I[2], I[3])};
    }
#pragma unroll
    for (int part = 0; part < 2; ++part) {
      const short* yt = part ? ytI : ytR;
#pragma unroll
      for (int h = 0; h < 2; ++h) {
        short8 unit = *(const short8*)&yt[l * 24 + h * 8];
        size_t line = (((size_t)(b * 5 + k) * 2 + part) * 16 + (q >> 1)) * 4 + (l >> 4);
        size_t idx = line * 64 + ((q & 1) * 2 + h) * 16 + (l & 15);
        yfrag[idx] = __builtin_bit_cast(u32x4, unit);
      }
    }
  }
}

// ---------------- k_main v11: R8's per-wave body, 1-wave blocks. Grid 6144 =
// 48b x 32it x 4 js-slices; the js-slice is a BLOCK coordinate, so occupancy
// is bounded only by VGPR (<=128 via waves_per_eu(4,4) -> 4 waves/SIMD,
// 16 waves/CU, 2.5x R8's residency). No LDS, no barriers. Each block writes
// its partial accumulators to ws; k_red sums the 4 slices.
__global__ __launch_bounds__(64) __attribute__((amdgpu_waves_per_eu(4, 4)))
void k_main(
    const float* __restrict__ lapr, const float* __restrict__ lapi,
    const float4* __restrict__ s4, const float4* __restrict__ stats,
    const float2* __restrict__ sj2, const u32x4* __restrict__ yfrag,
    const float* __restrict__ bar, const float* __restrict__ bai,
    const float* __restrict__ modbp,
    float* __restrict__ partR, float* __restrict__ partI)
{
  const int g = blockIdx.x;
  const int bl = g & 7;                 // XCD swizzle: same-b blocks co-located
  const int g2 = g >> 3;                // 0..767
  const int it = g2 & 31;
  const int sl = (g2 >> 5) & 3;         // js-slice 0..3
  const int bh = g2 >> 7;               // 0..5
  const int b = bl + (bh << 3);
  const int l = threadIdx.x;
  const int lane15 = l & 15, quad = l >> 4;
  const int gi = it * 16 + lane15;

  float ba_r = bar[0], ba_i = bai[0], modb = modbp[0];
  float4 sv = s4[(size_t)b * 512 + gi];
  float4 st = stats[(size_t)b * 512 + gi];
  float sirb = sv.x + ba_r, siib = sv.y + ba_i;
  float maxr = st.x, rsr = st.y, maxi = st.z, rsi = st.w;

  f32x4 accR[4], accI[4];
#pragma unroll
  for (int os = 0; os < 4; ++os) {
    accR[os] = f32x4{0.f, 0.f, 0.f, 0.f};
    accI[os] = f32x4{0.f, 0.f, 0.f, 0.f};
  }

  const size_t NN = (size_t)512 * 512;
  const float* lapr_b = lapr + ((size_t)b * 5 * 512 + gi) * 512;
  const float* lapi_b = lapi + ((size_t)b * 5 * 512 + gi) * 512;
  const u32x4* yb = yfrag + (size_t)b * 5 * 8192 + l;

  for (int jsw = 0; jsw < 4; ++jsw) {
    const int js = sl * 4 + jsw;
    const int jq = js * 32 + quad * 8;

    // --- issue sj loads, then ALL 20 lap loads (kept live together in VGPRs)
    const f32x4* sjp = (const f32x4*)(sj2 + (size_t)b * 512 + jq);
    f32x4 sjv0 = sjp[0], sjv1 = sjp[1], sjv2 = sjp[2], sjv3 = sjp[3];

    f32x4 LR[5][2], LI[5][2];
#pragma unroll
    for (int k = 0; k < 5; ++k) {
      const f32x4* pr = (const f32x4*)(lapr_b + (size_t)k * NN + jq);
      const f32x4* pi_ = (const f32x4*)(lapi_b + (size_t)k * NN + jq);
      LR[k][0] = __builtin_nontemporal_load(pr);
      LR[k][1] = __builtin_nontemporal_load(pr + 1);
      LI[k][0] = __builtin_nontemporal_load(pi_);
      LI[k][1] = __builtin_nontemporal_load(pi_ + 1);
    }
    __builtin_amdgcn_sched_barrier(0);   // pin load issue above the a-compute

    // --- a-compute: independent of lap loads, runs under their latency
    float sjr[8] = {sjv0[0], sjv0[2], sjv1[0], sjv1[2], sjv2[0], sjv2[2], sjv3[0], sjv3[2]};
    float sjimag[8] = {sjv0[1], sjv0[3], sjv1[1], sjv1[3], sjv2[1], sjv2[3], sjv3[1], sjv3[3]};
    float ar[8], ai[8];
#pragma unroll
    for (int e = 0; e < 8; ++e) {
      float scr = sirb + sjr[e];
      float sci = siib + sjimag[e];
      float mag = __builtin_amdgcn_sqrtf(fmaf(scr, scr, sci * sci));
      float sc = fmaxf(mag + modb, 0.f) * __builtin_amdgcn_rcpf(mag + EPSF);
      ar[e] = __expf(fmaf(scr, sc, -maxr)) * rsr;
      ai[e] = __expf(fmaf(sci, sc, -maxi)) * rsi;
    }

    // --- per k: pack A (short-lived), load B (L2), 16 MFMA
#pragma unroll
    for (int k = 0; k < 5; ++k) {
      float lrv[8], liv[8];
#pragma unroll
      for (int e = 0; e < 4; ++e) {
        lrv[e]     = LR[k][0][e] * ar[e]     - LI[k][0][e] * ai[e];
        liv[e]     = LR[k][0][e] * ai[e]     + LI[k][0][e] * ar[e];
        lrv[4 + e] = LR[k][1][e] * ar[4 + e] - LI[k][1][e] * ai[4 + e];
        liv[4 + e] = LR[k][1][e] * ai[4 + e] + LI[k][1][e] * ar[4 + e];
      }
      unsigned p0 = pkbf(lrv[0], lrv[1]), p1 = pkbf(lrv[2], lrv[3]);
      unsigned p2 = pkbf(lrv[4], lrv[5]), p3 = pkbf(lrv[6], lrv[7]);
      unsigned q0 = pkbf(liv[0], liv[1]), q1 = pkbf(liv[2], liv[3]);
      unsigned q2 = pkbf(liv[4], liv[5]), q3 = pkbf(liv[6], liv[7]);
      short8 Ar = mk8(p0, p1, p2, p3);
      short8 Ai = mk8(q0, q1, q2, q3);
      short8 An = mk8(q0 ^ 0x80008000u, q1 ^ 0x80008000u,
                      q2 ^ 0x80008000u, q3 ^ 0x80008000u);

      const u32x4* yk = yb + (size_t)k * 8192 + (size_t)(js * 4) * 64;
#pragma unroll
      for (int os = 0; os < 4; ++os) {
        short8 br8 = __builtin_bit_cast(short8, yk[os * 64]);
        short8 bi8 = __builtin_bit_cast(short8, yk[4096 + os * 64]);
        accR[os] = __builtin_amdgcn_mfma_f32_16x16x32_bf16(Ar, br8, accR[os], 0, 0, 0);
        accR[os] = __builtin_amdgcn_mfma_f32_16x16x32_bf16(An, bi8, accR[os], 0, 0, 0);
        accI[os] = __builtin_amdgcn_mfma_f32_16x16x32_bf16(Ar, bi8, accI[os], 0, 0, 0);
        accI[os] = __builtin_amdgcn_mfma_f32_16x16x32_bf16(Ai, br8, accI[os], 0, 0, 0);
      }
    }
  }

  // ---- write this slice's partials (summed by k_red)
  const size_t pbase = ((size_t)sl * 48 + b) * 512;
#pragma unroll
  for (int os = 0; os < 4; ++os) {
    int oc = os * 16 + lane15;
#pragma unroll
    for (int r = 0; r < 4; ++r) {
      size_t oidx = (pbase + it * 16 + quad * 4 + r) * 64 + oc;
      partR[oidx] = accR[os][r];
      partI[oidx] = accI[os][r];
    }
  }
}

// ---------------- k_red: out = sum over the 4 js-slice partials
__global__ __launch_bounds__(256) void k_red(
    const f32x4* __restrict__ partR, const f32x4* __restrict__ partI,
    f32x4* __restrict__ out_r, f32x4* __restrict__ out_i)
{
  const size_t NPART = (size_t)48 * 512 * 64 / 4;   // 393216 float4 per slice
  size_t x = (size_t)blockIdx.x * 256 + threadIdx.x;
  f32x4 r = partR[x] + partR[NPART + x] + partR[2 * NPART + x] + partR[3 * NPART + x];
  f32x4 i = partI[x] + partI[NPART + x] + partI[2 * NPART + x] + partI[3 * NPART + x];
  out_r[x] = r;
  out_i[x] = i;
}

extern "C" void kernel_launch(void* const* d_in, const int* in_sizes, int n_in,
                              void* d_out, int out_size, void* d_ws, size_t ws_size,
                              hipStream_t stream) {
  const float* Xr = (const float*)d_in[0];
  const float* Xi = (const float*)d_in[1];
  const float* lapr = (const float*)d_in[2];
  const float* lapi = (const float*)d_in[3];
  const float* War = (const float*)d_in[4];
  const float* Wai = (const float*)d_in[5];
  const float* bar = (const float*)d_in[6];
  const float* bai = (const float*)d_in[7];
  const float* modb = (const float*)d_in[8];
  const float* Wr = (const float*)d_in[9];
  const float* Wi = (const float*)d_in[10];

  // ws: s4 384KB | stats 384KB | sj2 192KB | yfrag 30MB | partR 25.2MB | partI 25.2MB
  char* wsb = (char*)d_ws;
  float4* s4 = (float4*)wsb;
  float4* stats = (float4*)(wsb + 393216);
  float2* sj2 = (float2*)(wsb + 786432);
  u32x4* yfrag = (u32x4*)(wsb + 983040);
  float* partR = (float*)(wsb + 983040 + 31457280);
  float* partI = partR + (size_t)4 * 48 * 512 * 64;

  float* out_r = (float*)d_out;
  float* out_i = out_r + (size_t)48 * 512 * 64;

  k_s<<<768, 256, 0, stream>>>(Xr, Xi, War, Wai, s4, sj2);
  k_stats<<<768, 256, 0, stream>>>(s4, sj2, bar, bai, modb, stats);
  k_y<<<960, 256, 0, stream>>>(Xr, Xi, Wr, Wi, yfrag);
  k_main<<<6144, 64, 0, stream>>>(lapr, lapi, s4, stats, sj2, yfrag,
                                  bar, bai, modb, partR, partI);
  k_red<<<1536, 256, 0, stream>>>((const f32x4*)partR, (const f32x4*)partI,
                                  (f32x4*)out_r, (f32x4*)out_i);
}

// Round 13
// 211.522 us; speedup vs baseline: 1.3867x; 1.3867x over previous
//
#include <hip/hip_runtime.h>

#define EPSF 1e-9f

typedef __attribute__((ext_vector_type(8))) short short8;
typedef __attribute__((ext_vector_type(4))) float f32x4;
typedef __attribute__((ext_vector_type(4))) unsigned int u32x4;
typedef __attribute__((ext_vector_type(2))) unsigned int u32x2;

__device__ __forceinline__ unsigned pkbf(float lo, float hi) {
  unsigned r;
  asm("v_cvt_pk_bf16_f32 %0, %1, %2" : "=v"(r) : "v"(lo), "v"(hi));
  return r;
}
__device__ __forceinline__ short8 mk8(unsigned a, unsigned b, unsigned c, unsigned d) {
  u32x4 u = {a, b, c, d};
  return __builtin_bit_cast(short8, u);
}

// ---------------- k_s: s[b,n] = (si_r, si_i, sj_r, sj_i); 8 lanes per row
__global__ __launch_bounds__(256) void k_s(
    const float* __restrict__ Xr, const float* __restrict__ Xi,
    const float* __restrict__ War, const float* __restrict__ Wai,
    float4* __restrict__ s4, float2* __restrict__ sj2)
{
  int t = threadIdx.x;
  int nf = blockIdx.x * 32 + (t >> 3);   // flat b*512+n
  int c0 = (t & 7) * 8;
  const f32x4* xr = (const f32x4*)(Xr + (size_t)nf * 64 + c0);
  const f32x4* xi = (const f32x4*)(Xi + (size_t)nf * 64 + c0);
  const f32x4* w1r = (const f32x4*)(War + c0);
  const f32x4* w2r = (const f32x4*)(War + 64 + c0);
  const f32x4* w1i = (const f32x4*)(Wai + c0);
  const f32x4* w2i = (const f32x4*)(Wai + 64 + c0);
  float sir = 0.f, sii = 0.f, sjr = 0.f, sji = 0.f;
#pragma unroll
  for (int h = 0; h < 2; ++h) {
    f32x4 a = xr[h], bb = xi[h];
    f32x4 u1r = w1r[h], u1i = w1i[h], u2r = w2r[h], u2i = w2i[h];
#pragma unroll
    for (int e = 0; e < 4; ++e) {
      sir += a[e] * u1r[e] - bb[e] * u1i[e];
      sii += a[e] * u1i[e] + bb[e] * u1r[e];
      sjr += a[e] * u2r[e] - bb[e] * u2i[e];
      sji += a[e] * u2i[e] + bb[e] * u2r[e];
    }
  }
#pragma unroll
  for (int off = 1; off < 8; off <<= 1) {
    sir += __shfl_xor(sir, off);
    sii += __shfl_xor(sii, off);
    sjr += __shfl_xor(sjr, off);
    sji += __shfl_xor(sji, off);
  }
  if ((t & 7) == 0) {
    s4[nf] = make_float4(sir, sii, sjr, sji);
    sj2[nf] = make_float2(sjr, sji);
  }
}

// ---------------- k_stats: per-(b,i) (max_r, 1/sum_r, max_i, 1/sum_i)
__global__ __launch_bounds__(256) void k_stats(
    const float4* __restrict__ s4, const float2* __restrict__ sj2,
    const float* __restrict__ bar, const float* __restrict__ bai,
    const float* __restrict__ modbp, float4* __restrict__ stats)
{
  __shared__ float2 sh[512];
  int t = threadIdx.x;
  int b = blockIdx.x >> 4;
  int i0 = (blockIdx.x & 15) * 32;
  sh[t] = sj2[(size_t)b * 512 + t];
  sh[t + 256] = sj2[(size_t)b * 512 + t + 256];
  __syncthreads();
  float ba_r = bar[0], ba_i = bai[0], modb = modbp[0];
  int i = i0 + (t >> 3), jl = t & 7;
  float4 sv = s4[(size_t)b * 512 + i];
  float sirb = sv.x + ba_r, siib = sv.y + ba_i;
  float mr = -1e30f, mi = -1e30f;
  for (int jj = 0; jj < 64; ++jj) {
    float2 sj = sh[jl * 64 + jj];
    float scr = sirb + sj.x, sci = siib + sj.y;
    float mag = sqrtf(scr * scr + sci * sci);
    float sc = fmaxf(mag + modb, 0.f) * __builtin_amdgcn_rcpf(mag + EPSF);
    mr = fmaxf(mr, scr * sc);
    mi = fmaxf(mi, sci * sc);
  }
#pragma unroll
  for (int off = 1; off < 8; off <<= 1) {
    mr = fmaxf(mr, __shfl_xor(mr, off));
    mi = fmaxf(mi, __shfl_xor(mi, off));
  }
  float er = 0.f, ei = 0.f;
  for (int jj = 0; jj < 64; ++jj) {
    float2 sj = sh[jl * 64 + jj];
    float scr = sirb + sj.x, sci = siib + sj.y;
    float mag = sqrtf(scr * scr + sci * sci);
    float sc = fmaxf(mag + modb, 0.f) * __builtin_amdgcn_rcpf(mag + EPSF);
    er += __expf(scr * sc - mr);
    ei += __expf(sci * sc - mi);
  }
#pragma unroll
  for (int off = 1; off < 8; off <<= 1) {
    er += __shfl_xor(er, off);
    ei += __shfl_xor(ei, off);
  }
  if (jl == 0)
    stats[(size_t)b * 512 + i] = make_float4(mr, 1.f / er, mi, 1.f / ei);
}

// ---------------- k_y: Y[b,k] = X[b] @ W[k] (complex), B-fragment layout.
// 960 blocks (R9-verified split): blockIdx = (b*5+k)*4 + jh; q = jh*8 + w*2 + qq.
__global__ __launch_bounds__(256) void k_y(
    const float* __restrict__ Xr, const float* __restrict__ Xi,
    const float* __restrict__ Wr, const float* __restrict__ Wi,
    u32x4* __restrict__ yfrag)
{
  __shared__ __align__(16) short WtR[64 * 72];     // [o][c] pad 72
  __shared__ __align__(16) short WtI[64 * 72];
  __shared__ __align__(16) short Yt[4][2][64 * 24]; // per-wave [o][jj] pad 24
  int bk = blockIdx.x >> 2;
  int jh = blockIdx.x & 3;
  int b = bk / 5, k = bk % 5;
  int t = threadIdx.x;
  {
    int o = t & 63, cbase = (t >> 6) * 16;
    const float* wr = Wr + (size_t)k * 4096;
    const float* wi = Wi + (size_t)k * 4096;
#pragma unroll
    for (int cc = 0; cc < 16; cc += 2) {
      int c = cbase + cc;
      *(unsigned*)&WtR[o * 72 + c] = pkbf(wr[c * 64 + o], wr[(c + 1) * 64 + o]);
      *(unsigned*)&WtI[o * 72 + c] = pkbf(wi[c * 64 + o], wi[(c + 1) * 64 + o]);
    }
  }
  __syncthreads();
  int w = t >> 6, l = t & 63;
  int lane15 = l & 15, quad = l >> 4;
  short* ytR = &Yt[w][0][0];
  short* ytI = &Yt[w][1][0];
  for (int qq = 0; qq < 2; ++qq) {
    int q = jh * 8 + w * 2 + qq;
    int j = q * 16 + lane15;
    const f32x4* pxr = (const f32x4*)(Xr + ((size_t)b * 512 + j) * 64 + quad * 8);
    const f32x4* pxi = (const f32x4*)(Xi + ((size_t)b * 512 + j) * 64 + quad * 8);
    f32x4 xr0 = pxr[0], xr1 = pxr[1], xr8 = pxr[8], xr9 = pxr[9];
    f32x4 xi0 = pxi[0], xi1 = pxi[1], xi8 = pxi[8], xi9 = pxi[9];
    short8 axr[2], axi[2];
    axr[0] = mk8(pkbf(xr0[0], xr0[1]), pkbf(xr0[2], xr0[3]), pkbf(xr1[0], xr1[1]), pkbf(xr1[2], xr1[3]));
    axr[1] = mk8(pkbf(xr8[0], xr8[1]), pkbf(xr8[2], xr8[3]), pkbf(xr9[0], xr9[1]), pkbf(xr9[2], xr9[3]));
    axi[0] = mk8(pkbf(xi0[0], xi0[1]), pkbf(xi0[2], xi0[3]), pkbf(xi1[0], xi1[1]), pkbf(xi1[2], xi1[3]));
    axi[1] = mk8(pkbf(xi8[0], xi8[1]), pkbf(xi8[2], xi8[3]), pkbf(xi9[0], xi9[1]), pkbf(xi9[2], xi9[3]));
    f32x4 aR1[4], aR2[4], aI[4];
#pragma unroll
    for (int os = 0; os < 4; ++os) {
      aR1[os] = f32x4{0.f, 0.f, 0.f, 0.f};
      aR2[os] = f32x4{0.f, 0.f, 0.f, 0.f};
      aI[os] = f32x4{0.f, 0.f, 0.f, 0.f};
    }
#pragma unroll
    for (int kc = 0; kc < 2; ++kc) {
#pragma unroll
      for (int os = 0; os < 4; ++os) {
        int widx = (os * 16 + lane15) * 72 + kc * 32 + quad * 8;
        short8 wrF = *(const short8*)&WtR[widx];
        short8 wiF = *(const short8*)&WtI[widx];
        aR1[os] = __builtin_amdgcn_mfma_f32_16x16x32_bf16(axr[kc], wrF, aR1[os], 0, 0, 0);
        aR2[os] = __builtin_amdgcn_mfma_f32_16x16x32_bf16(axi[kc], wiF, aR2[os], 0, 0, 0);
        aI[os]  = __builtin_amdgcn_mfma_f32_16x16x32_bf16(axr[kc], wiF, aI[os], 0, 0, 0);
        aI[os]  = __builtin_amdgcn_mfma_f32_16x16x32_bf16(axi[kc], wrF, aI[os], 0, 0, 0);
      }
    }
#pragma unroll
    for (int os = 0; os < 4; ++os) {
      f32x4 R = aR1[os] - aR2[os];
      f32x4 I = aI[os];
      int ya = (os * 16 + lane15) * 24 + quad * 4;
      *(u32x2*)&ytR[ya] = u32x2{pkbf(R[0], R[1]), pkbf(R[2], R[3])};
      *(u32x2*)&ytI[ya] = u32x2{pkbf(I[0], I[1]), pkbf(I[2], I[3])};
    }
#pragma unroll
    for (int part = 0; part < 2; ++part) {
      const short* yt = part ? ytI : ytR;
#pragma unroll
      for (int h = 0; h < 2; ++h) {
        short8 unit = *(const short8*)&yt[l * 24 + h * 8];
        size_t line = (((size_t)(b * 5 + k) * 2 + part) * 16 + (q >> 1)) * 4 + (l >> 4);
        size_t idx = line * 64 + ((q & 1) * 2 + h) * 16 + (l & 15);
        yfrag[idx] = __builtin_bit_cast(u32x4, unit);
      }
    }
  }
}

// ---------------- k_main v12: R12 body with the waves_per_eu cap REMOVED.
// 1-wave blocks, grid 6144 (48b x 32it x 4 js-slices); no LDS, no barriers —
// residency bounded only by the true register footprint. R12's (4,4) both
// capped occupancy at 16/CU and squeezed VGPR to 64 (serializing the load
// cluster); default allocation should restore per-wave depth while the
// 24 blocks/CU grid provides the TLP that R3 showed drives BW.
__global__ __launch_bounds__(64)
void k_main(
    const float* __restrict__ lapr, const float* __restrict__ lapi,
    const float4* __restrict__ s4, const float4* __restrict__ stats,
    const float2* __restrict__ sj2, const u32x4* __restrict__ yfrag,
    const float* __restrict__ bar, const float* __restrict__ bai,
    const float* __restrict__ modbp,
    float* __restrict__ partR, float* __restrict__ partI)
{
  const int g = blockIdx.x;
  const int bl = g & 7;                 // XCD swizzle: same-b blocks co-located
  const int g2 = g >> 3;                // 0..767
  const int it = g2 & 31;
  const int sl = (g2 >> 5) & 3;         // js-slice 0..3
  const int bh = g2 >> 7;               // 0..5
  const int b = bl + (bh << 3);
  const int l = threadIdx.x;
  const int lane15 = l & 15, quad = l >> 4;
  const int gi = it * 16 + lane15;

  float ba_r = bar[0], ba_i = bai[0], modb = modbp[0];
  float4 sv = s4[(size_t)b * 512 + gi];
  float4 st = stats[(size_t)b * 512 + gi];
  float sirb = sv.x + ba_r, siib = sv.y + ba_i;
  float maxr = st.x, rsr = st.y, maxi = st.z, rsi = st.w;

  f32x4 accR[4], accI[4];
#pragma unroll
  for (int os = 0; os < 4; ++os) {
    accR[os] = f32x4{0.f, 0.f, 0.f, 0.f};
    accI[os] = f32x4{0.f, 0.f, 0.f, 0.f};
  }

  const size_t NN = (size_t)512 * 512;
  const float* lapr_b = lapr + ((size_t)b * 5 * 512 + gi) * 512;
  const float* lapi_b = lapi + ((size_t)b * 5 * 512 + gi) * 512;
  const u32x4* yb = yfrag + (size_t)b * 5 * 8192 + l;

  for (int jsw = 0; jsw < 4; ++jsw) {
    const int js = sl * 4 + jsw;
    const int jq = js * 32 + quad * 8;

    // --- issue sj loads, then ALL 20 lap loads (kept live together in VGPRs)
    const f32x4* sjp = (const f32x4*)(sj2 + (size_t)b * 512 + jq);
    f32x4 sjv0 = sjp[0], sjv1 = sjp[1], sjv2 = sjp[2], sjv3 = sjp[3];

    f32x4 LR[5][2], LI[5][2];
#pragma unroll
    for (int k = 0; k < 5; ++k) {
      const f32x4* pr = (const f32x4*)(lapr_b + (size_t)k * NN + jq);
      const f32x4* pi_ = (const f32x4*)(lapi_b + (size_t)k * NN + jq);
      LR[k][0] = __builtin_nontemporal_load(pr);
      LR[k][1] = __builtin_nontemporal_load(pr + 1);
      LI[k][0] = __builtin_nontemporal_load(pi_);
      LI[k][1] = __builtin_nontemporal_load(pi_ + 1);
    }
    __builtin_amdgcn_sched_barrier(0);   // pin load issue above the a-compute

    // --- a-compute: independent of lap loads, runs under their latency
    float sjr[8] = {sjv0[0], sjv0[2], sjv1[0], sjv1[2], sjv2[0], sjv2[2], sjv3[0], sjv3[2]};
    float sjimag[8] = {sjv0[1], sjv0[3], sjv1[1], sjv1[3], sjv2[1], sjv2[3], sjv3[1], sjv3[3]};
    float ar[8], ai[8];
#pragma unroll
    for (int e = 0; e < 8; ++e) {
      float scr = sirb + sjr[e];
      float sci = siib + sjimag[e];
      float mag = __builtin_amdgcn_sqrtf(fmaf(scr, scr, sci * sci));
      float sc = fmaxf(mag + modb, 0.f) * __builtin_amdgcn_rcpf(mag + EPSF);
      ar[e] = __expf(fmaf(scr, sc, -maxr)) * rsr;
      ai[e] = __expf(fmaf(sci, sc, -maxi)) * rsi;
    }

    // --- per k: pack A (short-lived), load B (L2), 16 MFMA
#pragma unroll
    for (int k = 0; k < 5; ++k) {
      float lrv[8], liv[8];
#pragma unroll
      for (int e = 0; e < 4; ++e) {
        lrv[e]     = LR[k][0][e] * ar[e]     - LI[k][0][e] * ai[e];
        liv[e]     = LR[k][0][e] * ai[e]     + LI[k][0][e] * ar[e];
        lrv[4 + e] = LR[k][1][e] * ar[4 + e] - LI[k][1][e] * ai[4 + e];
        liv[4 + e] = LR[k][1][e] * ai[4 + e] + LI[k][1][e] * ar[4 + e];
      }
      unsigned p0 = pkbf(lrv[0], lrv[1]), p1 = pkbf(lrv[2], lrv[3]);
      unsigned p2 = pkbf(lrv[4], lrv[5]), p3 = pkbf(lrv[6], lrv[7]);
      unsigned q0 = pkbf(liv[0], liv[1]), q1 = pkbf(liv[2], liv[3]);
      unsigned q2 = pkbf(liv[4], liv[5]), q3 = pkbf(liv[6], liv[7]);
      short8 Ar = mk8(p0, p1, p2, p3);
      short8 Ai = mk8(q0, q1, q2, q3);
      short8 An = mk8(q0 ^ 0x80008000u, q1 ^ 0x80008000u,
                      q2 ^ 0x80008000u, q3 ^ 0x80008000u);

      const u32x4* yk = yb + (size_t)k * 8192 + (size_t)(js * 4) * 64;
#pragma unroll
      for (int os = 0; os < 4; ++os) {
        short8 br8 = __builtin_bit_cast(short8, yk[os * 64]);
        short8 bi8 = __builtin_bit_cast(short8, yk[4096 + os * 64]);
        accR[os] = __builtin_amdgcn_mfma_f32_16x16x32_bf16(Ar, br8, accR[os], 0, 0, 0);
        accR[os] = __builtin_amdgcn_mfma_f32_16x16x32_bf16(An, bi8, accR[os], 0, 0, 0);
        accI[os] = __builtin_amdgcn_mfma_f32_16x16x32_bf16(Ar, bi8, accI[os], 0, 0, 0);
        accI[os] = __builtin_amdgcn_mfma_f32_16x16x32_bf16(Ai, br8, accI[os], 0, 0, 0);
      }
    }
  }

  // ---- write this slice's partials (summed by k_red)
  const size_t pbase = ((size_t)sl * 48 + b) * 512;
#pragma unroll
  for (int os = 0; os < 4; ++os) {
    int oc = os * 16 + lane15;
#pragma unroll
    for (int r = 0; r < 4; ++r) {
      size_t oidx = (pbase + it * 16 + quad * 4 + r) * 64 + oc;
      partR[oidx] = accR[os][r];
      partI[oidx] = accI[os][r];
    }
  }
}

// ---------------- k_red: out = sum over the 4 js-slice partials
__global__ __launch_bounds__(256) void k_red(
    const f32x4* __restrict__ partR, const f32x4* __restrict__ partI,
    f32x4* __restrict__ out_r, f32x4* __restrict__ out_i)
{
  const size_t NPART = (size_t)48 * 512 * 64 / 4;   // 393216 float4 per slice
  size_t x = (size_t)blockIdx.x * 256 + threadIdx.x;
  f32x4 r = partR[x] + partR[NPART + x] + partR[2 * NPART + x] + partR[3 * NPART + x];
  f32x4 i = partI[x] + partI[NPART + x] + partI[2 * NPART + x] + partI[3 * NPART + x];
  out_r[x] = r;
  out_i[x] = i;
}

extern "C" void kernel_launch(void* const* d_in, const int* in_sizes, int n_in,
                              void* d_out, int out_size, void* d_ws, size_t ws_size,
                              hipStream_t stream) {
  const float* Xr = (const float*)d_in[0];
  const float* Xi = (const float*)d_in[1];
  const float* lapr = (const float*)d_in[2];
  const float* lapi = (const float*)d_in[3];
  const float* War = (const float*)d_in[4];
  const float* Wai = (const float*)d_in[5];
  const float* bar = (const float*)d_in[6];
  const float* bai = (const float*)d_in[7];
  const float* modb = (const float*)d_in[8];
  const float* Wr = (const float*)d_in[9];
  const float* Wi = (const float*)d_in[10];

  // ws: s4 384KB | stats 384KB | sj2 192KB | yfrag 30MB | partR 25.2MB | partI 25.2MB
  char* wsb = (char*)d_ws;
  float4* s4 = (float4*)wsb;
  float4* stats = (float4*)(wsb + 393216);
  float2* sj2 = (float2*)(wsb + 786432);
  u32x4* yfrag = (u32x4*)(wsb + 983040);
  float* partR = (float*)(wsb + 983040 + 31457280);
  float* partI = partR + (size_t)4 * 48 * 512 * 64;

  float* out_r = (float*)d_out;
  float* out_i = out_r + (size_t)48 * 512 * 64;

  k_s<<<768, 256, 0, stream>>>(Xr, Xi, War, Wai, s4, sj2);
  k_stats<<<768, 256, 0, stream>>>(s4, sj2, bar, bai, modb, stats);
  k_y<<<960, 256, 0, stream>>>(Xr, Xi, Wr, Wi, yfrag);
  k_main<<<6144, 64, 0, stream>>>(lapr, lapi, s4, stats, sj2, yfrag,
                                  bar, bai, modb, partR, partI);
  k_red<<<1536, 256, 0, stream>>>((const f32x4*)partR, (const f32x4*)partI,
                                  (f32x4*)out_r, (f32x4*)out_i);
}

// Round 15
// 195.422 us; speedup vs baseline: 1.5009x; 1.0824x over previous
//
#include <hip/hip_runtime.h>

#define EPSF 1e-9f

typedef __attribute__((ext_vector_type(8))) short short8;
typedef __attribute__((ext_vector_type(4))) float f32x4;
typedef __attribute__((ext_vector_type(4))) unsigned int u32x4;
typedef __attribute__((ext_vector_type(2))) unsigned int u32x2;

__device__ __forceinline__ unsigned pkbf(float lo, float hi) {
  unsigned r;
  asm("v_cvt_pk_bf16_f32 %0, %1, %2" : "=v"(r) : "v"(lo), "v"(hi));
  return r;
}
__device__ __forceinline__ short8 mk8(unsigned a, unsigned b, unsigned c, unsigned d) {
  u32x4 u = {a, b, c, d};
  return __builtin_bit_cast(short8, u);
}

// ---------------- k_s: s[b,n] = (si_r, si_i, sj_r, sj_i); 8 lanes per row
__global__ __launch_bounds__(256) void k_s(
    const float* __restrict__ Xr, const float* __restrict__ Xi,
    const float* __restrict__ War, const float* __restrict__ Wai,
    float4* __restrict__ s4, float2* __restrict__ sj2)
{
  int t = threadIdx.x;
  int nf = blockIdx.x * 32 + (t >> 3);   // flat b*512+n
  int c0 = (t & 7) * 8;
  const f32x4* xr = (const f32x4*)(Xr + (size_t)nf * 64 + c0);
  const f32x4* xi = (const f32x4*)(Xi + (size_t)nf * 64 + c0);
  const f32x4* w1r = (const f32x4*)(War + c0);
  const f32x4* w2r = (const f32x4*)(War + 64 + c0);
  const f32x4* w1i = (const f32x4*)(Wai + c0);
  const f32x4* w2i = (const f32x4*)(Wai + 64 + c0);
  float sir = 0.f, sii = 0.f, sjr = 0.f, sji = 0.f;
#pragma unroll
  for (int h = 0; h < 2; ++h) {
    f32x4 a = xr[h], bb = xi[h];
    f32x4 u1r = w1r[h], u1i = w1i[h], u2r = w2r[h], u2i = w2i[h];
#pragma unroll
    for (int e = 0; e < 4; ++e) {
      sir += a[e] * u1r[e] - bb[e] * u1i[e];
      sii += a[e] * u1i[e] + bb[e] * u1r[e];
      sjr += a[e] * u2r[e] - bb[e] * u2i[e];
      sji += a[e] * u2i[e] + bb[e] * u2r[e];
    }
  }
#pragma unroll
  for (int off = 1; off < 8; off <<= 1) {
    sir += __shfl_xor(sir, off);
    sii += __shfl_xor(sii, off);
    sjr += __shfl_xor(sjr, off);
    sji += __shfl_xor(sji, off);
  }
  if ((t & 7) == 0) {
    s4[nf] = make_float4(sir, sii, sjr, sji);
    sj2[nf] = make_float2(sjr, sji);
  }
}

// ---------------- k_stats: per-(b,i) (max_r, 1/sum_r, max_i, 1/sum_i)
__global__ __launch_bounds__(256) void k_stats(
    const float4* __restrict__ s4, const float2* __restrict__ sj2,
    const float* __restrict__ bar, const float* __restrict__ bai,
    const float* __restrict__ modbp, float4* __restrict__ stats)
{
  __shared__ float2 sh[512];
  int t = threadIdx.x;
  int b = blockIdx.x >> 4;
  int i0 = (blockIdx.x & 15) * 32;
  sh[t] = sj2[(size_t)b * 512 + t];
  sh[t + 256] = sj2[(size_t)b * 512 + t + 256];
  __syncthreads();
  float ba_r = bar[0], ba_i = bai[0], modb = modbp[0];
  int i = i0 + (t >> 3), jl = t & 7;
  float4 sv = s4[(size_t)b * 512 + i];
  float sirb = sv.x + ba_r, siib = sv.y + ba_i;
  float mr = -1e30f, mi = -1e30f;
  for (int jj = 0; jj < 64; ++jj) {
    float2 sj = sh[jl * 64 + jj];
    float scr = sirb + sj.x, sci = siib + sj.y;
    float mag = sqrtf(scr * scr + sci * sci);
    float sc = fmaxf(mag + modb, 0.f) * __builtin_amdgcn_rcpf(mag + EPSF);
    mr = fmaxf(mr, scr * sc);
    mi = fmaxf(mi, sci * sc);
  }
#pragma unroll
  for (int off = 1; off < 8; off <<= 1) {
    mr = fmaxf(mr, __shfl_xor(mr, off));
    mi = fmaxf(mi, __shfl_xor(mi, off));
  }
  float er = 0.f, ei = 0.f;
  for (int jj = 0; jj < 64; ++jj) {
    float2 sj = sh[jl * 64 + jj];
    float scr = sirb + sj.x, sci = siib + sj.y;
    float mag = sqrtf(scr * scr + sci * sci);
    float sc = fmaxf(mag + modb, 0.f) * __builtin_amdgcn_rcpf(mag + EPSF);
    er += __expf(scr * sc - mr);
    ei += __expf(sci * sc - mi);
  }
#pragma unroll
  for (int off = 1; off < 8; off <<= 1) {
    er += __shfl_xor(er, off);
    ei += __shfl_xor(ei, off);
  }
  if (jl == 0)
    stats[(size_t)b * 512 + i] = make_float4(mr, 1.f / er, mi, 1.f / ei);
}

// ---------------- k_y: Y[b,k] = X[b] @ W[k] (complex), B-fragment layout.
// 960 blocks (verified R9/R12/R13): blockIdx = (b*5+k)*4 + jh; q = jh*8 + w*2 + qq.
__global__ __launch_bounds__(256) void k_y(
    const float* __restrict__ Xr, const float* __restrict__ Xi,
    const float* __restrict__ Wr, const float* __restrict__ Wi,
    u32x4* __restrict__ yfrag)
{
  __shared__ __align__(16) short WtR[64 * 72];     // [o][c] pad 72
  __shared__ __align__(16) short WtI[64 * 72];
  __shared__ __align__(16) short Yt[4][2][64 * 24]; // per-wave [o][jj] pad 24
  int bk = blockIdx.x >> 2;
  int jh = blockIdx.x & 3;
  int b = bk / 5, k = bk % 5;
  int t = threadIdx.x;
  {
    int o = t & 63, cbase = (t >> 6) * 16;
    const float* wr = Wr + (size_t)k * 4096;
    const float* wi = Wi + (size_t)k * 4096;
#pragma unroll
    for (int cc = 0; cc < 16; cc += 2) {
      int c = cbase + cc;
      *(unsigned*)&WtR[o * 72 + c] = pkbf(wr[c * 64 + o], wr[(c + 1) * 64 + o]);
      *(unsigned*)&WtI[o * 72 + c] = pkbf(wi[c * 64 + o], wi[(c + 1) * 64 + o]);
    }
  }
  __syncthreads();
  int w = t >> 6, l = t & 63;
  int lane15 = l & 15, quad = l >> 4;
  short* ytR = &Yt[w][0][0];
  short* ytI = &Yt[w][1][0];
  for (int qq = 0; qq < 2; ++qq) {
    int q = jh * 8 + w * 2 + qq;
    int j = q * 16 + lane15;
    const f32x4* pxr = (const f32x4*)(Xr + ((size_t)b * 512 + j) * 64 + quad * 8);
    const f32x4* pxi = (const f32x4*)(Xi + ((size_t)b * 512 + j) * 64 + quad * 8);
    f32x4 xr0 = pxr[0], xr1 = pxr[1], xr8 = pxr[8], xr9 = pxr[9];
    f32x4 xi0 = pxi[0], xi1 = pxi[1], xi8 = pxi[8], xi9 = pxi[9];
    short8 axr[2], axi[2];
    axr[0] = mk8(pkbf(xr0[0], xr0[1]), pkbf(xr0[2], xr0[3]), pkbf(xr1[0], xr1[1]), pkbf(xr1[2], xr1[3]));
    axr[1] = mk8(pkbf(xr8[0], xr8[1]), pkbf(xr8[2], xr8[3]), pkbf(xr9[0], xr9[1]), pkbf(xr9[2], xr9[3]));
    axi[0] = mk8(pkbf(xi0[0], xi0[1]), pkbf(xi0[2], xi0[3]), pkbf(xi1[0], xi1[1]), pkbf(xi1[2], xi1[3]));
    axi[1] = mk8(pkbf(xi8[0], xi8[1]), pkbf(xi8[2], xi8[3]), pkbf(xi9[0], xi9[1]), pkbf(xi9[2], xi9[3]));
    f32x4 aR1[4], aR2[4], aI[4];
#pragma unroll
    for (int os = 0; os < 4; ++os) {
      aR1[os] = f32x4{0.f, 0.f, 0.f, 0.f};
      aR2[os] = f32x4{0.f, 0.f, 0.f, 0.f};
      aI[os] = f32x4{0.f, 0.f, 0.f, 0.f};
    }
#pragma unroll
    for (int kc = 0; kc < 2; ++kc) {
#pragma unroll
      for (int os = 0; os < 4; ++os) {
        int widx = (os * 16 + lane15) * 72 + kc * 32 + quad * 8;
        short8 wrF = *(const short8*)&WtR[widx];
        short8 wiF = *(const short8*)&WtI[widx];
        aR1[os] = __builtin_amdgcn_mfma_f32_16x16x32_bf16(axr[kc], wrF, aR1[os], 0, 0, 0);
        aR2[os] = __builtin_amdgcn_mfma_f32_16x16x32_bf16(axi[kc], wiF, aR2[os], 0, 0, 0);
        aI[os]  = __builtin_amdgcn_mfma_f32_16x16x32_bf16(axr[kc], wiF, aI[os], 0, 0, 0);
        aI[os]  = __builtin_amdgcn_mfma_f32_16x16x32_bf16(axi[kc], wrF, aI[os], 0, 0, 0);
      }
    }
#pragma unroll
    for (int os = 0; os < 4; ++os) {
      f32x4 R = aR1[os] - aR2[os];
      f32x4 I = aI[os];
      int ya = (os * 16 + lane15) * 24 + quad * 4;
      *(u32x2*)&ytR[ya] = u32x2{pkbf(R[0], R[1]), pkbf(R[2], R[3])};
      *(u32x2*)&ytI[ya] = u32x2{pkbf(I[0], I[1]), pkbf(I[2], I[3])};
    }
#pragma unroll
    for (int part = 0; part < 2; ++part) {
      const short* yt = part ? ytI : ytR;
#pragma unroll
      for (int h = 0; h < 2; ++h) {
        short8 unit = *(const short8*)&yt[l * 24 + h * 8];
        size_t line = (((size_t)(b * 5 + k) * 2 + part) * 16 + (q >> 1)) * 4 + (l >> 4);
        size_t idx = line * 64 + ((q & 1) * 2 + h) * 16 + (l & 15);
        yfrag[idx] = __builtin_bit_cast(u32x4, unit);
      }
    }
  }
}

// ---------------- k_main: R8's passing source, byte-for-byte (144 µs, twice-
// verified). waves_per_eu(2,2) keeps the 20-load cluster live (VGPR~104);
// nt lap loads; j-split across 4 waves; a-compute under load latency;
// per-k inline y-loads + 16 MFMA; original f32x4 tree-reduce epilogue.
__global__ __launch_bounds__(256) __attribute__((amdgpu_waves_per_eu(2, 2)))
void k_main(
    const float* __restrict__ lapr, const float* __restrict__ lapi,
    const float4* __restrict__ s4, const float4* __restrict__ stats,
    const float2* __restrict__ sj2, const u32x4* __restrict__ yfrag,
    const float* __restrict__ bar, const float* __restrict__ bai,
    const float* __restrict__ modbp,
    float* __restrict__ out_r, float* __restrict__ out_i)
{
  __shared__ __align__(16) f32x4 red[2][64][8];   // 16 KB tree-reduce buffer

  const int g = blockIdx.x;
  const int b = (g & 7) + ((g >> 8) << 3);   // XCD swizzle (1536 = 8*192, bijective)
  const int it = (g >> 3) & 31;
  const int t = threadIdx.x;
  const int w = t >> 6;                      // wave = js-slice 0..3
  const int l = t & 63;
  const int lane15 = l & 15, quad = l >> 4;
  const int gi = it * 16 + lane15;

  float ba_r = bar[0], ba_i = bai[0], modb = modbp[0];
  float4 sv = s4[(size_t)b * 512 + gi];
  float4 st = stats[(size_t)b * 512 + gi];
  float sirb = sv.x + ba_r, siib = sv.y + ba_i;
  float maxr = st.x, rsr = st.y, maxi = st.z, rsi = st.w;

  f32x4 accR[4], accI[4];
#pragma unroll
  for (int os = 0; os < 4; ++os) {
    accR[os] = f32x4{0.f, 0.f, 0.f, 0.f};
    accI[os] = f32x4{0.f, 0.f, 0.f, 0.f};
  }

  const size_t NN = (size_t)512 * 512;
  const float* lapr_b = lapr + ((size_t)b * 5 * 512 + gi) * 512;
  const float* lapi_b = lapi + ((size_t)b * 5 * 512 + gi) * 512;
  const u32x4* yb = yfrag + (size_t)b * 5 * 8192 + l;

  for (int jsw = 0; jsw < 4; ++jsw) {
    const int js = w * 4 + jsw;
    const int jq = js * 32 + quad * 8;

    // --- issue sj loads, then ALL 20 lap loads (kept live together in VGPRs)
    const f32x4* sjp = (const f32x4*)(sj2 + (size_t)b * 512 + jq);
    f32x4 sjv0 = sjp[0], sjv1 = sjp[1], sjv2 = sjp[2], sjv3 = sjp[3];

    f32x4 LR[5][2], LI[5][2];
#pragma unroll
    for (int k = 0; k < 5; ++k) {
      const f32x4* pr = (const f32x4*)(lapr_b + (size_t)k * NN + jq);
      const f32x4* pi_ = (const f32x4*)(lapi_b + (size_t)k * NN + jq);
      LR[k][0] = __builtin_nontemporal_load(pr);
      LR[k][1] = __builtin_nontemporal_load(pr + 1);
      LI[k][0] = __builtin_nontemporal_load(pi_);
      LI[k][1] = __builtin_nontemporal_load(pi_ + 1);
    }
    __builtin_amdgcn_sched_barrier(0);   // pin load issue above the a-compute

    // --- a-compute: independent of lap loads, runs under their latency
    float sjr[8] = {sjv0[0], sjv0[2], sjv1[0], sjv1[2], sjv2[0], sjv2[2], sjv3[0], sjv3[2]};
    float sjimag[8] = {sjv0[1], sjv0[3], sjv1[1], sjv1[3], sjv2[1], sjv2[3], sjv3[1], sjv3[3]};
    float ar[8], ai[8];
#pragma unroll
    for (int e = 0; e < 8; ++e) {
      float scr = sirb + sjr[e];
      float sci = siib + sjimag[e];
      float mag = __builtin_amdgcn_sqrtf(fmaf(scr, scr, sci * sci));
      float sc = fmaxf(mag + modb, 0.f) * __builtin_amdgcn_rcpf(mag + EPSF);
      ar[e] = __expf(fmaf(scr, sc, -maxr)) * rsr;
      ai[e] = __expf(fmaf(sci, sc, -maxi)) * rsi;
    }

    // --- per k: pack A (short-lived), load B (L2), 16 MFMA
#pragma unroll
    for (int k = 0; k < 5; ++k) {
      float lrv[8], liv[8];
#pragma unroll
      for (int e = 0; e < 4; ++e) {
        lrv[e]     = LR[k][0][e] * ar[e]     - LI[k][0][e] * ai[e];
        liv[e]     = LR[k][0][e] * ai[e]     + LI[k][0][e] * ar[e];
        lrv[4 + e] = LR[k][1][e] * ar[4 + e] - LI[k][1][e] * ai[4 + e];
        liv[4 + e] = LR[k][1][e] * ai[4 + e] + LI[k][1][e] * ar[4 + e];
      }
      unsigned p0 = pkbf(lrv[0], lrv[1]), p1 = pkbf(lrv[2], lrv[3]);
      unsigned p2 = pkbf(lrv[4], lrv[5]), p3 = pkbf(lrv[6], lrv[7]);
      unsigned q0 = pkbf(liv[0], liv[1]), q1 = pkbf(liv[2], liv[3]);
      unsigned q2 = pkbf(liv[4], liv[5]), q3 = pkbf(liv[6], liv[7]);
      short8 Ar = mk8(p0, p1, p2, p3);
      short8 Ai = mk8(q0, q1, q2, q3);
      short8 An = mk8(q0 ^ 0x80008000u, q1 ^ 0x80008000u,
                      q2 ^ 0x80008000u, q3 ^ 0x80008000u);

      const u32x4* yk = yb + (size_t)k * 8192 + (size_t)(js * 4) * 64;
#pragma unroll
      for (int os = 0; os < 4; ++os) {
        short8 br8 = __builtin_bit_cast(short8, yk[os * 64]);
        short8 bi8 = __builtin_bit_cast(short8, yk[4096 + os * 64]);
        accR[os] = __builtin_amdgcn_mfma_f32_16x16x32_bf16(Ar, br8, accR[os], 0, 0, 0);
        accR[os] = __builtin_amdgcn_mfma_f32_16x16x32_bf16(An, bi8, accR[os], 0, 0, 0);
        accI[os] = __builtin_amdgcn_mfma_f32_16x16x32_bf16(Ar, bi8, accI[os], 0, 0, 0);
        accI[os] = __builtin_amdgcn_mfma_f32_16x16x32_bf16(Ai, br8, accI[os], 0, 0, 0);
      }
    }
  }

  // ---- tree-reduce partial sums across the 4 waves
  if (w >= 2) {
#pragma unroll
    for (int os = 0; os < 4; ++os) {
      red[w - 2][l][os] = accR[os];
      red[w - 2][l][4 + os] = accI[os];
    }
  }
  __syncthreads();
  if (w < 2) {
#pragma unroll
    for (int os = 0; os < 4; ++os) {
      accR[os] += red[w][l][os];
      accI[os] += red[w][l][4 + os];
    }
  }
  __syncthreads();
  if (w == 1) {
#pragma unroll
    for (int os = 0; os < 4; ++os) {
      red[0][l][os] = accR[os];
      red[0][l][4 + os] = accI[os];
    }
  }
  __syncthreads();
  if (w == 0) {
#pragma unroll
    for (int os = 0; os < 4; ++os) {
      accR[os] += red[0][l][os];
      accI[os] += red[0][l][4 + os];
      int oc = os * 16 + lane15;
#pragma unroll
      for (int r = 0; r < 4; ++r) {
        size_t oidx = ((size_t)b * 512 + it * 16 + quad * 4 + r) * 64 + oc;
        out_r[oidx] = accR[os][r];
        out_i[oidx] = accI[os][r];
      }
    }
  }
}

extern "C" void kernel_launch(void* const* d_in, const int* in_sizes, int n_in,
                              void* d_out, int out_size, void* d_ws, size_t ws_size,
                              hipStream_t stream) {
  const float* Xr = (const float*)d_in[0];
  const float* Xi = (const float*)d_in[1];
  const float* lapr = (const float*)d_in[2];
  const float* lapi = (const float*)d_in[3];
  const float* War = (const float*)d_in[4];
  const float* Wai = (const float*)d_in[5];
  const float* bar = (const float*)d_in[6];
  const float* bai = (const float*)d_in[7];
  const float* modb = (const float*)d_in[8];
  const float* Wr = (const float*)d_in[9];
  const float* Wi = (const float*)d_in[10];

  // ws layout: s4 384KB | stats 384KB | sj2 192KB | yfrag 30MB  (total ~31.7MB)
  char* wsb = (char*)d_ws;
  float4* s4 = (float4*)wsb;
  float4* stats = (float4*)(wsb + 393216);
  float2* sj2 = (float2*)(wsb + 786432);
  u32x4* yfrag = (u32x4*)(wsb + 983040);

  float* out_r = (float*)d_out;
  float* out_i = out_r + (size_t)48 * 512 * 64;

  k_s<<<768, 256, 0, stream>>>(Xr, Xi, War, Wai, s4, sj2);
  k_stats<<<768, 256, 0, stream>>>(s4, sj2, bar, bai, modb, stats);
  k_y<<<960, 256, 0, stream>>>(Xr, Xi, Wr, Wi, yfrag);
  k_main<<<1536, 256, 0, stream>>>(lapr, lapi, s4, stats, sj2, yfrag,
                                   bar, bai, modb, out_r, out_i);
}

// Round 16
// 195.355 us; speedup vs baseline: 1.5014x; 1.0003x over previous
//
#include <hip/hip_runtime.h>

#define EPSF 1e-9f

typedef __attribute__((ext_vector_type(8))) short short8;
typedef __attribute__((ext_vector_type(4))) float f32x4;
typedef __attribute__((ext_vector_type(4))) unsigned int u32x4;
typedef __attribute__((ext_vector_type(2))) unsigned int u32x2;

__device__ __forceinline__ unsigned pkbf(float lo, float hi) {
  unsigned r;
  asm("v_cvt_pk_bf16_f32 %0, %1, %2" : "=v"(r) : "v"(lo), "v"(hi));
  return r;
}
__device__ __forceinline__ short8 mk8(unsigned a, unsigned b, unsigned c, unsigned d) {
  u32x4 u = {a, b, c, d};
  return __builtin_bit_cast(short8, u);
}

// ---------------- k_s: s[b,n] = (si_r, si_i, sj_r, sj_i); 8 lanes per row
__global__ __launch_bounds__(256) void k_s(
    const float* __restrict__ Xr, const float* __restrict__ Xi,
    const float* __restrict__ War, const float* __restrict__ Wai,
    float4* __restrict__ s4, float2* __restrict__ sj2)
{
  int t = threadIdx.x;
  int nf = blockIdx.x * 32 + (t >> 3);   // flat b*512+n
  int c0 = (t & 7) * 8;
  const f32x4* xr = (const f32x4*)(Xr + (size_t)nf * 64 + c0);
  const f32x4* xi = (const f32x4*)(Xi + (size_t)nf * 64 + c0);
  const f32x4* w1r = (const f32x4*)(War + c0);
  const f32x4* w2r = (const f32x4*)(War + 64 + c0);
  const f32x4* w1i = (const f32x4*)(Wai + c0);
  const f32x4* w2i = (const f32x4*)(Wai + 64 + c0);
  float sir = 0.f, sii = 0.f, sjr = 0.f, sji = 0.f;
#pragma unroll
  for (int h = 0; h < 2; ++h) {
    f32x4 a = xr[h], bb = xi[h];
    f32x4 u1r = w1r[h], u1i = w1i[h], u2r = w2r[h], u2i = w2i[h];
#pragma unroll
    for (int e = 0; e < 4; ++e) {
      sir += a[e] * u1r[e] - bb[e] * u1i[e];
      sii += a[e] * u1i[e] + bb[e] * u1r[e];
      sjr += a[e] * u2r[e] - bb[e] * u2i[e];
      sji += a[e] * u2i[e] + bb[e] * u2r[e];
    }
  }
#pragma unroll
  for (int off = 1; off < 8; off <<= 1) {
    sir += __shfl_xor(sir, off);
    sii += __shfl_xor(sii, off);
    sjr += __shfl_xor(sjr, off);
    sji += __shfl_xor(sji, off);
  }
  if ((t & 7) == 0) {
    s4[nf] = make_float4(sir, sii, sjr, sji);
    sj2[nf] = make_float2(sjr, sji);
  }
}

// ---------------- k_stats: per-(b,i) (max_r, 1/sum_r, max_i, 1/sum_i)
__global__ __launch_bounds__(256) void k_stats(
    const float4* __restrict__ s4, const float2* __restrict__ sj2,
    const float* __restrict__ bar, const float* __restrict__ bai,
    const float* __restrict__ modbp, float4* __restrict__ stats)
{
  __shared__ float2 sh[512];
  int t = threadIdx.x;
  int b = blockIdx.x >> 4;
  int i0 = (blockIdx.x & 15) * 32;
  sh[t] = sj2[(size_t)b * 512 + t];
  sh[t + 256] = sj2[(size_t)b * 512 + t + 256];
  __syncthreads();
  float ba_r = bar[0], ba_i = bai[0], modb = modbp[0];
  int i = i0 + (t >> 3), jl = t & 7;
  float4 sv = s4[(size_t)b * 512 + i];
  float sirb = sv.x + ba_r, siib = sv.y + ba_i;
  float mr = -1e30f, mi = -1e30f;
  for (int jj = 0; jj < 64; ++jj) {
    float2 sj = sh[jl * 64 + jj];
    float scr = sirb + sj.x, sci = siib + sj.y;
    float mag = sqrtf(scr * scr + sci * sci);
    float sc = fmaxf(mag + modb, 0.f) * __builtin_amdgcn_rcpf(mag + EPSF);
    mr = fmaxf(mr, scr * sc);
    mi = fmaxf(mi, sci * sc);
  }
#pragma unroll
  for (int off = 1; off < 8; off <<= 1) {
    mr = fmaxf(mr, __shfl_xor(mr, off));
    mi = fmaxf(mi, __shfl_xor(mi, off));
  }
  float er = 0.f, ei = 0.f;
  for (int jj = 0; jj < 64; ++jj) {
    float2 sj = sh[jl * 64 + jj];
    float scr = sirb + sj.x, sci = siib + sj.y;
    float mag = sqrtf(scr * scr + sci * sci);
    float sc = fmaxf(mag + modb, 0.f) * __builtin_amdgcn_rcpf(mag + EPSF);
    er += __expf(scr * sc - mr);
    ei += __expf(sci * sc - mi);
  }
#pragma unroll
  for (int off = 1; off < 8; off <<= 1) {
    er += __shfl_xor(er, off);
    ei += __shfl_xor(ei, off);
  }
  if (jl == 0)
    stats[(size_t)b * 512 + i] = make_float4(mr, 1.f / er, mi, 1.f / ei);
}

// ---------------- k_y: Y[b,k] = X[b] @ W[k] (complex), B-fragment layout.
// 960 blocks (verified R9/R12/R13): blockIdx = (b*5+k)*4 + jh; q = jh*8 + w*2 + qq.
__global__ __launch_bounds__(256) void k_y(
    const float* __restrict__ Xr, const float* __restrict__ Xi,
    const float* __restrict__ Wr, const float* __restrict__ Wi,
    u32x4* __restrict__ yfrag)
{
  __shared__ __align__(16) short WtR[64 * 72];     // [o][c] pad 72
  __shared__ __align__(16) short WtI[64 * 72];
  __shared__ __align__(16) short Yt[4][2][64 * 24]; // per-wave [o][jj] pad 24
  int bk = blockIdx.x >> 2;
  int jh = blockIdx.x & 3;
  int b = bk / 5, k = bk % 5;
  int t = threadIdx.x;
  {
    int o = t & 63, cbase = (t >> 6) * 16;
    const float* wr = Wr + (size_t)k * 4096;
    const float* wi = Wi + (size_t)k * 4096;
#pragma unroll
    for (int cc = 0; cc < 16; cc += 2) {
      int c = cbase + cc;
      *(unsigned*)&WtR[o * 72 + c] = pkbf(wr[c * 64 + o], wr[(c + 1) * 64 + o]);
      *(unsigned*)&WtI[o * 72 + c] = pkbf(wi[c * 64 + o], wi[(c + 1) * 64 + o]);
    }
  }
  __syncthreads();
  int w = t >> 6, l = t & 63;
  int lane15 = l & 15, quad = l >> 4;
  short* ytR = &Yt[w][0][0];
  short* ytI = &Yt[w][1][0];
  for (int qq = 0; qq < 2; ++qq) {
    int q = jh * 8 + w * 2 + qq;
    int j = q * 16 + lane15;
    const f32x4* pxr = (const f32x4*)(Xr + ((size_t)b * 512 + j) * 64 + quad * 8);
    const f32x4* pxi = (const f32x4*)(Xi + ((size_t)b * 512 + j) * 64 + quad * 8);
    f32x4 xr0 = pxr[0], xr1 = pxr[1], xr8 = pxr[8], xr9 = pxr[9];
    f32x4 xi0 = pxi[0], xi1 = pxi[1], xi8 = pxi[8], xi9 = pxi[9];
    short8 axr[2], axi[2];
    axr[0] = mk8(pkbf(xr0[0], xr0[1]), pkbf(xr0[2], xr0[3]), pkbf(xr1[0], xr1[1]), pkbf(xr1[2], xr1[3]));
    axr[1] = mk8(pkbf(xr8[0], xr8[1]), pkbf(xr8[2], xr8[3]), pkbf(xr9[0], xr9[1]), pkbf(xr9[2], xr9[3]));
    axi[0] = mk8(pkbf(xi0[0], xi0[1]), pkbf(xi0[2], xi0[3]), pkbf(xi1[0], xi1[1]), pkbf(xi1[2], xi1[3]));
    axi[1] = mk8(pkbf(xi8[0], xi8[1]), pkbf(xi8[2], xi8[3]), pkbf(xi9[0], xi9[1]), pkbf(xi9[2], xi9[3]));
    f32x4 aR1[4], aR2[4], aI[4];
#pragma unroll
    for (int os = 0; os < 4; ++os) {
      aR1[os] = f32x4{0.f, 0.f, 0.f, 0.f};
      aR2[os] = f32x4{0.f, 0.f, 0.f, 0.f};
      aI[os] = f32x4{0.f, 0.f, 0.f, 0.f};
    }
#pragma unroll
    for (int kc = 0; kc < 2; ++kc) {
#pragma unroll
      for (int os = 0; os < 4; ++os) {
        int widx = (os * 16 + lane15) * 72 + kc * 32 + quad * 8;
        short8 wrF = *(const short8*)&WtR[widx];
        short8 wiF = *(const short8*)&WtI[widx];
        aR1[os] = __builtin_amdgcn_mfma_f32_16x16x32_bf16(axr[kc], wrF, aR1[os], 0, 0, 0);
        aR2[os] = __builtin_amdgcn_mfma_f32_16x16x32_bf16(axi[kc], wiF, aR2[os], 0, 0, 0);
        aI[os]  = __builtin_amdgcn_mfma_f32_16x16x32_bf16(axr[kc], wiF, aI[os], 0, 0, 0);
        aI[os]  = __builtin_amdgcn_mfma_f32_16x16x32_bf16(axi[kc], wrF, aI[os], 0, 0, 0);
      }
    }
#pragma unroll
    for (int os = 0; os < 4; ++os) {
      f32x4 R = aR1[os] - aR2[os];
      f32x4 I = aI[os];
      int ya = (os * 16 + lane15) * 24 + quad * 4;
      *(u32x2*)&ytR[ya] = u32x2{pkbf(R[0], R[1]), pkbf(R[2], R[3])};
      *(u32x2*)&ytI[ya] = u32x2{pkbf(I[0], I[1]), pkbf(I[2], I[3])};
    }
#pragma unroll
    for (int part = 0; part < 2; ++part) {
      const short* yt = part ? ytI : ytR;
#pragma unroll
      for (int h = 0; h < 2; ++h) {
        short8 unit = *(const short8*)&yt[l * 24 + h * 8];
        size_t line = (((size_t)(b * 5 + k) * 2 + part) * 16 + (q >> 1)) * 4 + (l >> 4);
        size_t idx = line * 64 + ((q & 1) * 2 + h) * 16 + (l & 15);
        yfrag[idx] = __builtin_bit_cast(u32x4, unit);
      }
    }
  }
}

// ---------------- k_main: R8's passing source, byte-for-byte (144 µs, twice-
// verified). waves_per_eu(2,2) keeps the 20-load cluster live (VGPR~104);
// nt lap loads; j-split across 4 waves; a-compute under load latency;
// per-k inline y-loads + 16 MFMA; original f32x4 tree-reduce epilogue.
__global__ __launch_bounds__(256) __attribute__((amdgpu_waves_per_eu(2, 2)))
void k_main(
    const float* __restrict__ lapr, const float* __restrict__ lapi,
    const float4* __restrict__ s4, const float4* __restrict__ stats,
    const float2* __restrict__ sj2, const u32x4* __restrict__ yfrag,
    const float* __restrict__ bar, const float* __restrict__ bai,
    const float* __restrict__ modbp,
    float* __restrict__ out_r, float* __restrict__ out_i)
{
  __shared__ __align__(16) f32x4 red[2][64][8];   // 16 KB tree-reduce buffer

  const int g = blockIdx.x;
  const int b = (g & 7) + ((g >> 8) << 3);   // XCD swizzle (1536 = 8*192, bijective)
  const int it = (g >> 3) & 31;
  const int t = threadIdx.x;
  const int w = t >> 6;                      // wave = js-slice 0..3
  const int l = t & 63;
  const int lane15 = l & 15, quad = l >> 4;
  const int gi = it * 16 + lane15;

  float ba_r = bar[0], ba_i = bai[0], modb = modbp[0];
  float4 sv = s4[(size_t)b * 512 + gi];
  float4 st = stats[(size_t)b * 512 + gi];
  float sirb = sv.x + ba_r, siib = sv.y + ba_i;
  float maxr = st.x, rsr = st.y, maxi = st.z, rsi = st.w;

  f32x4 accR[4], accI[4];
#pragma unroll
  for (int os = 0; os < 4; ++os) {
    accR[os] = f32x4{0.f, 0.f, 0.f, 0.f};
    accI[os] = f32x4{0.f, 0.f, 0.f, 0.f};
  }

  const size_t NN = (size_t)512 * 512;
  const float* lapr_b = lapr + ((size_t)b * 5 * 512 + gi) * 512;
  const float* lapi_b = lapi + ((size_t)b * 5 * 512 + gi) * 512;
  const u32x4* yb = yfrag + (size_t)b * 5 * 8192 + l;

  for (int jsw = 0; jsw < 4; ++jsw) {
    const int js = w * 4 + jsw;
    const int jq = js * 32 + quad * 8;

    // --- issue sj loads, then ALL 20 lap loads (kept live together in VGPRs)
    const f32x4* sjp = (const f32x4*)(sj2 + (size_t)b * 512 + jq);
    f32x4 sjv0 = sjp[0], sjv1 = sjp[1], sjv2 = sjp[2], sjv3 = sjp[3];

    f32x4 LR[5][2], LI[5][2];
#pragma unroll
    for (int k = 0; k < 5; ++k) {
      const f32x4* pr = (const f32x4*)(lapr_b + (size_t)k * NN + jq);
      const f32x4* pi_ = (const f32x4*)(lapi_b + (size_t)k * NN + jq);
      LR[k][0] = __builtin_nontemporal_load(pr);
      LR[k][1] = __builtin_nontemporal_load(pr + 1);
      LI[k][0] = __builtin_nontemporal_load(pi_);
      LI[k][1] = __builtin_nontemporal_load(pi_ + 1);
    }
    __builtin_amdgcn_sched_barrier(0);   // pin load issue above the a-compute

    // --- a-compute: independent of lap loads, runs under their latency
    float sjr[8] = {sjv0[0], sjv0[2], sjv1[0], sjv1[2], sjv2[0], sjv2[2], sjv3[0], sjv3[2]};
    float sjimag[8] = {sjv0[1], sjv0[3], sjv1[1], sjv1[3], sjv2[1], sjv2[3], sjv3[1], sjv3[3]};
    float ar[8], ai[8];
#pragma unroll
    for (int e = 0; e < 8; ++e) {
      float scr = sirb + sjr[e];
      float sci = siib + sjimag[e];
      float mag = __builtin_amdgcn_sqrtf(fmaf(scr, scr, sci * sci));
      float sc = fmaxf(mag + modb, 0.f) * __builtin_amdgcn_rcpf(mag + EPSF);
      ar[e] = __expf(fmaf(scr, sc, -maxr)) * rsr;
      ai[e] = __expf(fmaf(sci, sc, -maxi)) * rsi;
    }

    // --- per k: pack A (short-lived), load B (L2), 16 MFMA
#pragma unroll
    for (int k = 0; k < 5; ++k) {
      float lrv[8], liv[8];
#pragma unroll
      for (int e = 0; e < 4; ++e) {
        lrv[e]     = LR[k][0][e] * ar[e]     - LI[k][0][e] * ai[e];
        liv[e]     = LR[k][0][e] * ai[e]     + LI[k][0][e] * ar[e];
        lrv[4 + e] = LR[k][1][e] * ar[4 + e] - LI[k][1][e] * ai[4 + e];
        liv[4 + e] = LR[k][1][e] * ai[4 + e] + LI[k][1][e] * ar[4 + e];
      }
      unsigned p0 = pkbf(lrv[0], lrv[1]), p1 = pkbf(lrv[2], lrv[3]);
      unsigned p2 = pkbf(lrv[4], lrv[5]), p3 = pkbf(lrv[6], lrv[7]);
      unsigned q0 = pkbf(liv[0], liv[1]), q1 = pkbf(liv[2], liv[3]);
      unsigned q2 = pkbf(liv[4], liv[5]), q3 = pkbf(liv[6], liv[7]);
      short8 Ar = mk8(p0, p1, p2, p3);
      short8 Ai = mk8(q0, q1, q2, q3);
      short8 An = mk8(q0 ^ 0x80008000u, q1 ^ 0x80008000u,
                      q2 ^ 0x80008000u, q3 ^ 0x80008000u);

      const u32x4* yk = yb + (size_t)k * 8192 + (size_t)(js * 4) * 64;
#pragma unroll
      for (int os = 0; os < 4; ++os) {
        short8 br8 = __builtin_bit_cast(short8, yk[os * 64]);
        short8 bi8 = __builtin_bit_cast(short8, yk[4096 + os * 64]);
        accR[os] = __builtin_amdgcn_mfma_f32_16x16x32_bf16(Ar, br8, accR[os], 0, 0, 0);
        accR[os] = __builtin_amdgcn_mfma_f32_16x16x32_bf16(An, bi8, accR[os], 0, 0, 0);
        accI[os] = __builtin_amdgcn_mfma_f32_16x16x32_bf16(Ar, bi8, accI[os], 0, 0, 0);
        accI[os] = __builtin_amdgcn_mfma_f32_16x16x32_bf16(Ai, br8, accI[os], 0, 0, 0);
      }
    }
  }

  // ---- tree-reduce partial sums across the 4 waves
  if (w >= 2) {
#pragma unroll
    for (int os = 0; os < 4; ++os) {
      red[w - 2][l][os] = accR[os];
      red[w - 2][l][4 + os] = accI[os];
    }
  }
  __syncthreads();
  if (w < 2) {
#pragma unroll
    for (int os = 0; os < 4; ++os) {
      accR[os] += red[w][l][os];
      accI[os] += red[w][l][4 + os];
    }
  }
  __syncthreads();
  if (w == 1) {
#pragma unroll
    for (int os = 0; os < 4; ++os) {
      red[0][l][os] = accR[os];
      red[0][l][4 + os] = accI[os];
    }
  }
  __syncthreads();
  if (w == 0) {
#pragma unroll
    for (int os = 0; os < 4; ++os) {
      accR[os] += red[0][l][os];
      accI[os] += red[0][l][4 + os];
      int oc = os * 16 + lane15;
#pragma unroll
      for (int r = 0; r < 4; ++r) {
        size_t oidx = ((size_t)b * 512 + it * 16 + quad * 4 + r) * 64 + oc;
        out_r[oidx] = accR[os][r];
        out_i[oidx] = accI[os][r];
      }
    }
  }
}

extern "C" void kernel_launch(void* const* d_in, const int* in_sizes, int n_in,
                              void* d_out, int out_size, void* d_ws, size_t ws_size,
                              hipStream_t stream) {
  const float* Xr = (const float*)d_in[0];
  const float* Xi = (const float*)d_in[1];
  const float* lapr = (const float*)d_in[2];
  const float* lapi = (const float*)d_in[3];
  const float* War = (const float*)d_in[4];
  const float* Wai = (const float*)d_in[5];
  const float* bar = (const float*)d_in[6];
  const float* bai = (const float*)d_in[7];
  const float* modb = (const float*)d_in[8];
  const float* Wr = (const float*)d_in[9];
  const float* Wi = (const float*)d_in[10];

  // ws layout: s4 384KB | stats 384KB | sj2 192KB | yfrag 30MB  (total ~31.7MB)
  char* wsb = (char*)d_ws;
  float4* s4 = (float4*)wsb;
  float4* stats = (float4*)(wsb + 393216);
  float2* sj2 = (float2*)(wsb + 786432);
  u32x4* yfrag = (u32x4*)(wsb + 983040);

  float* out_r = (float*)d_out;
  float* out_i = out_r + (size_t)48 * 512 * 64;

  k_s<<<768, 256, 0, stream>>>(Xr, Xi, War, Wai, s4, sj2);
  k_stats<<<768, 256, 0, stream>>>(s4, sj2, bar, bai, modb, stats);
  k_y<<<960, 256, 0, stream>>>(Xr, Xi, Wr, Wi, yfrag);
  k_main<<<1536, 256, 0, stream>>>(lapr, lapi, s4, stats, sj2, yfrag,
                                   bar, bai, modb, out_r, out_i);
}